// Round 2
// baseline (1007.025 us; speedup 1.0000x reference)
//
#include <hip/hip_runtime.h>
#include <math.h>

#define N_QUBITS 11
#define N_LAYERS 2
#define DIM 2048
#define NLOC 32                 // amplitudes per lane (bits 0..4 local, bits 5..10 = lane)
#define N_GATES (N_LAYERS * N_QUBITS)

// One wave (64 threads) per batch element. Statevector lives entirely in
// VGPRs: lane L holds amplitudes i = L*32 + n, n = 0..31.
//  - qubit q in 0..4  : in-register butterfly (fully unrolled, const indices)
//  - qubit q in 5..10 : __shfl_xor lane exchange
//  - CNOT ladder      : fused into ONE permutation i_src = j ^ (j<<1)
//                       (prefix-xor inverse), applied via ds_bpermute.
// Gate matrices (22 x 2x2 complex) go through 704 B of LDS, read as
// same-address broadcasts (conflict-free).
__global__ __launch_bounds__(64, 4)
void pqc_sim_kernel(const float* __restrict__ theta,
                    const int* __restrict__ positions,
                    float* __restrict__ out)
{
    __shared__ float G[N_GATES][8];   // u00r,u00i,u01r,u01i,u10r,u10i,u11r,u11i

    const int b = blockIdx.x;
    const int L = threadIdx.x;        // lane 0..63
    const int pos = positions[b];

    // ---- Gate precompute: U = Rz(g) * Ry(b) * Rx(a), angles * 0.5 ----
    if (L < N_GATES) {
        const int l = L / N_QUBITS;
        const int q = L % N_QUBITS;
        const float* th = theta + (((size_t)pos * N_LAYERS + l) * (3 * N_QUBITS)) + 3 * q;
        const float a  = th[0] * 0.5f;
        const float bb = th[1] * 0.5f;
        const float g  = th[2] * 0.5f;
        float sa, ca, sb, cb, sg, cg;
        sincosf(a,  &sa, &ca);
        sincosf(bb, &sb, &cb);
        sincosf(g,  &sg, &cg);
        // M = Ry*Rx
        const float m00r =  cb * ca, m00i =  sb * sa;
        const float m01r = -sb * ca, m01i = -cb * sa;
        const float m10r =  sb * ca, m10i = -cb * sa;
        const float m11r =  cb * ca, m11i = -sb * sa;
        // Row 0 *= e^{-ig}; Row 1 *= e^{+ig}
        G[L][0] = m00r * cg + m00i * sg;  G[L][1] = m00i * cg - m00r * sg;
        G[L][2] = m01r * cg + m01i * sg;  G[L][3] = m01i * cg - m01r * sg;
        G[L][4] = m10r * cg - m10i * sg;  G[L][5] = m10i * cg + m10r * sg;
        G[L][6] = m11r * cg - m11i * sg;  G[L][7] = m11i * cg + m11r * sg;
    }
    __syncthreads();

    // ---- Register-resident state, |0...0> ----
    float sr[NLOC], si[NLOC];
    #pragma unroll
    for (int n = 0; n < NLOC; ++n) { sr[n] = 0.0f; si[n] = 0.0f; }
    if (L == 0) sr[0] = 1.0f;

    #pragma unroll 1
    for (int l = 0; l < N_LAYERS; ++l) {
        const int gbase = l * N_QUBITS;

        // ---- Local gates: qubits 0..4 (register butterflies) ----
        #pragma unroll
        for (int q = 0; q < 5; ++q) {
            const float u00r = G[gbase + q][0], u00i = G[gbase + q][1];
            const float u01r = G[gbase + q][2], u01i = G[gbase + q][3];
            const float u10r = G[gbase + q][4], u10i = G[gbase + q][5];
            const float u11r = G[gbase + q][6], u11i = G[gbase + q][7];
            #pragma unroll
            for (int p = 0; p < 16; ++p) {
                const int i0 = ((p >> q) << (q + 1)) | (p & ((1 << q) - 1));
                const int i1 = i0 | (1 << q);
                const float s0r = sr[i0], s0i = si[i0];
                const float s1r = sr[i1], s1i = si[i1];
                sr[i0] = u00r * s0r - u00i * s0i + u01r * s1r - u01i * s1i;
                si[i0] = u00r * s0i + u00i * s0r + u01r * s1i + u01i * s1r;
                sr[i1] = u10r * s0r - u10i * s0i + u11r * s1r - u11i * s1i;
                si[i1] = u10r * s0i + u10i * s0r + u11r * s1i + u11i * s1r;
            }
        }

        // ---- Lane gates: qubits 5..10 (shfl_xor exchange) ----
        #pragma unroll
        for (int q = 5; q < N_QUBITS; ++q) {
            const float u00r = G[gbase + q][0], u00i = G[gbase + q][1];
            const float u01r = G[gbase + q][2], u01i = G[gbase + q][3];
            const float u10r = G[gbase + q][4], u10i = G[gbase + q][5];
            const float u11r = G[gbase + q][6], u11i = G[gbase + q][7];
            const int mask = 1 << (q - 5);
            const int bit  = (L >> (q - 5)) & 1;
            // self coefficient / partner coefficient per lane row
            const float csr = bit ? u11r : u00r;
            const float csi = bit ? u11i : u00i;
            const float cpr = bit ? u10r : u01r;
            const float cpi = bit ? u10i : u01i;
            #pragma unroll
            for (int n = 0; n < NLOC; ++n) {
                const float pr = __shfl_xor(sr[n], mask);
                const float pi = __shfl_xor(si[n], mask);
                const float ar = sr[n], ai = si[n];
                sr[n] = csr * ar - csi * ai + cpr * pr - cpi * pi;
                si[n] = csr * ai + csi * ar + cpr * pi + cpi * pr;
            }
        }

        // ---- Fused CNOT ladder: dest j reads src i = j ^ (j<<1) ----
        // srcLocal(n) = (n ^ (n<<1)) & 31 (compile-time), srcLane = base ^ n4
        const int base = (L ^ (L << 1)) & 63;
        float nr[NLOC], ni[NLOC];
        #pragma unroll
        for (int n = 0; n < NLOC; ++n) {
            const int m  = (n ^ (n << 1)) & 31;
            const int sl = base ^ ((n >> 4) & 1);
            nr[n] = __shfl(sr[m], sl);
            ni[n] = __shfl(si[m], sl);
        }
        #pragma unroll
        for (int n = 0; n < NLOC; ++n) { sr[n] = nr[n]; si[n] = ni[n]; }
    }

    // ---- Epilogue: real part; lane L owns 32 consecutive floats ----
    float* orow = out + (size_t)b * DIM + L * NLOC;
    #pragma unroll
    for (int n = 0; n < NLOC; n += 4) {
        *(float4*)(orow + n) = make_float4(sr[n], sr[n+1], sr[n+2], sr[n+3]);
    }
}

extern "C" void kernel_launch(void* const* d_in, const int* in_sizes, int n_in,
                              void* d_out, int out_size, void* d_ws, size_t ws_size,
                              hipStream_t stream)
{
    const float* theta     = (const float*)d_in[0];
    const int*   positions = (const int*)d_in[1];
    float*       out       = (float*)d_out;
    const int B = in_sizes[1];   // 4096

    pqc_sim_kernel<<<B, 64, 0, stream>>>(theta, positions, out);
}

// Round 3
// 108.982 us; speedup vs baseline: 9.2403x; 9.2403x over previous
//
#include <hip/hip_runtime.h>
#include <math.h>

#define N_QUBITS 11
#define N_LAYERS 2
#define DIM 2048
#define NLOC 32                 // amplitudes per lane: i = L*32 + n
#define N_GATES (N_LAYERS * N_QUBITS)

// One wave (64 threads) per batch element; statevector fully in VGPRs.
//  - qubits 0..4 : in-register butterflies (const indices after unroll)
//  - qubits 5..10: __shfl_xor lane exchange
//  - CNOT ladder : fused permutation i_src = j ^ (j<<1), factored as
//      (a) in-place per-register lane shuffle  sr[m] <- lane (base ^ parity(m))
//      (b) register-index cycle renames        s[n] <- s[(n^(n<<1))&31]
//    so NO temp array (the round-2 nr/ni temps pushed live floats >= 128 and
//    the compiler demoted the state to scratch: 3.5 GB HBM traffic, 890 us).
__global__ __launch_bounds__(64, 4)
void pqc_sim_kernel(const float* __restrict__ theta,
                    const int* __restrict__ positions,
                    float* __restrict__ out)
{
    __shared__ float G[N_GATES][8];   // u00r,u00i,u01r,u01i,u10r,u10i,u11r,u11i

    const int b = blockIdx.x;
    const int L = threadIdx.x;        // lane 0..63
    const int pos = positions[b];

    // ---- Gate precompute: U = Rz(g) * Ry(b) * Rx(a), angles * 0.5 ----
    if (L < N_GATES) {
        const int l = L / N_QUBITS;
        const int q = L % N_QUBITS;
        const float* th = theta + (((size_t)pos * N_LAYERS + l) * (3 * N_QUBITS)) + 3 * q;
        const float a  = th[0] * 0.5f;
        const float bb = th[1] * 0.5f;
        const float g  = th[2] * 0.5f;
        float sa, ca, sb, cb, sg, cg;
        sincosf(a,  &sa, &ca);
        sincosf(bb, &sb, &cb);
        sincosf(g,  &sg, &cg);
        // M = Ry*Rx
        const float m00r =  cb * ca, m00i =  sb * sa;
        const float m01r = -sb * ca, m01i = -cb * sa;
        const float m10r =  sb * ca, m10i = -cb * sa;
        const float m11r =  cb * ca, m11i = -sb * sa;
        // Row 0 *= e^{-ig}; Row 1 *= e^{+ig}
        G[L][0] = m00r * cg + m00i * sg;  G[L][1] = m00i * cg - m00r * sg;
        G[L][2] = m01r * cg + m01i * sg;  G[L][3] = m01i * cg - m01r * sg;
        G[L][4] = m10r * cg - m10i * sg;  G[L][5] = m10i * cg + m10r * sg;
        G[L][6] = m11r * cg - m11i * sg;  G[L][7] = m11i * cg + m11r * sg;
    }
    __syncthreads();

    // ---- Register-resident state, |0...0> ----
    float sr[NLOC], si[NLOC];
    #pragma unroll
    for (int n = 0; n < NLOC; ++n) { sr[n] = 0.0f; si[n] = 0.0f; }
    if (L == 0) sr[0] = 1.0f;

    const int base = (L ^ (L << 1)) & 63;

    #pragma unroll
    for (int l = 0; l < N_LAYERS; ++l) {
        const int gbase = l * N_QUBITS;

        // ---- Local gates: qubits 0..4 (register butterflies) ----
        #pragma unroll
        for (int q = 0; q < 5; ++q) {
            const float u00r = G[gbase + q][0], u00i = G[gbase + q][1];
            const float u01r = G[gbase + q][2], u01i = G[gbase + q][3];
            const float u10r = G[gbase + q][4], u10i = G[gbase + q][5];
            const float u11r = G[gbase + q][6], u11i = G[gbase + q][7];
            #pragma unroll
            for (int p = 0; p < 16; ++p) {
                const int i0 = ((p >> q) << (q + 1)) | (p & ((1 << q) - 1));
                const int i1 = i0 | (1 << q);
                const float s0r = sr[i0], s0i = si[i0];
                const float s1r = sr[i1], s1i = si[i1];
                sr[i0] = u00r * s0r - u00i * s0i + u01r * s1r - u01i * s1i;
                si[i0] = u00r * s0i + u00i * s0r + u01r * s1i + u01i * s1r;
                sr[i1] = u10r * s0r - u10i * s0i + u11r * s1r - u11i * s1i;
                si[i1] = u10r * s0i + u10i * s0r + u11r * s1i + u11i * s1r;
            }
        }

        // ---- Lane gates: qubits 5..10 (shfl_xor exchange) ----
        #pragma unroll
        for (int q = 5; q < N_QUBITS; ++q) {
            const float u00r = G[gbase + q][0], u00i = G[gbase + q][1];
            const float u01r = G[gbase + q][2], u01i = G[gbase + q][3];
            const float u10r = G[gbase + q][4], u10i = G[gbase + q][5];
            const float u11r = G[gbase + q][6], u11i = G[gbase + q][7];
            const int mask = 1 << (q - 5);
            const int bit  = (L >> (q - 5)) & 1;
            const float csr = bit ? u11r : u00r;
            const float csi = bit ? u11i : u00i;
            const float cpr = bit ? u10r : u01r;
            const float cpi = bit ? u10i : u01i;
            #pragma unroll
            for (int n = 0; n < NLOC; ++n) {
                const float pr = __shfl_xor(sr[n], mask);
                const float pi = __shfl_xor(si[n], mask);
                const float ar = sr[n], ai = si[n];
                sr[n] = csr * ar - csi * ai + cpr * pr - cpi * pi;
                si[n] = csr * ai + csi * ar + cpr * pi + cpi * pr;
            }
        }

        // ---- Fused CNOT ladder, step (a): in-place lane shuffle per register.
        // dest(L,n) <- src(base^n4, f(n)); applied to register m = f(n), the
        // needed src lane is base ^ bit4(f^-1(m)) = base ^ parity(m).
        #pragma unroll
        for (int m = 0; m < NLOC; ++m) {
            const int sl = base ^ (__popc((unsigned)m) & 1);
            sr[m] = __shfl(sr[m], sl);
            si[m] = __shfl(si[m], sl);
        }

        // ---- step (b): register rename s[n] <- s[f(n)], f(n)=(n^(n<<1))&31,
        // as explicit cycles (one scalar temp each; compiler renames).
        #define CYC2(A,a0,a1) { float t=A[a0]; A[a0]=A[a1]; A[a1]=t; }
        #define CYC4(A,a0,a1,a2,a3) { float t=A[a0]; A[a0]=A[a1]; A[a1]=A[a2]; A[a2]=A[a3]; A[a3]=t; }
        #define CYC8(A,a0,a1,a2,a3,a4,a5,a6,a7) { float t=A[a0]; A[a0]=A[a1]; A[a1]=A[a2]; A[a2]=A[a3]; A[a3]=A[a4]; A[a4]=A[a5]; A[a5]=A[a6]; A[a6]=A[a7]; A[a7]=t; }
        CYC8(sr, 1,3,5,15,17,19,21,31);   CYC8(si, 1,3,5,15,17,19,21,31);
        CYC8(sr, 7,9,27,13,23,25,11,29);  CYC8(si, 7,9,27,13,23,25,11,29);
        CYC4(sr, 2,6,10,30);              CYC4(si, 2,6,10,30);
        CYC4(sr, 4,12,20,28);             CYC4(si, 4,12,20,28);
        CYC4(sr, 14,18,22,26);            CYC4(si, 14,18,22,26);
        CYC2(sr, 8,24);                   CYC2(si, 8,24);
        #undef CYC2
        #undef CYC4
        #undef CYC8
    }

    // ---- Epilogue: real part; lane L owns 32 consecutive floats ----
    float* orow = out + (size_t)b * DIM + L * NLOC;
    #pragma unroll
    for (int n = 0; n < NLOC; n += 4) {
        *(float4*)(orow + n) = make_float4(sr[n], sr[n+1], sr[n+2], sr[n+3]);
    }
}

extern "C" void kernel_launch(void* const* d_in, const int* in_sizes, int n_in,
                              void* d_out, int out_size, void* d_ws, size_t ws_size,
                              hipStream_t stream)
{
    const float* theta     = (const float*)d_in[0];
    const int*   positions = (const int*)d_in[1];
    float*       out       = (float*)d_out;
    const int B = in_sizes[1];   // 4096

    pqc_sim_kernel<<<B, 64, 0, stream>>>(theta, positions, out);
}